// Round 13
// baseline (529.410 us; speedup 1.0000x reference)
//
#include <hip/hip_runtime.h>
#include <cstddef>
#include <cstdint>

// Problem constants (from reference): B=256, T=512, I=128, H=64, 4H=256.
#define NB 256
#define NT 512
#define H4 256

typedef _Float16 v2h __attribute__((ext_vector_type(2)));
typedef int v4i __attribute__((ext_vector_type(4)));

// Quad-lane exchange via DPP quad_perm (pure VALU):
// xor1: perm(1,0,3,2)=0xB1 ; xor2: perm(2,3,0,1)=0x4E
__device__ __forceinline__ float dpp_xor1(float x) {
    int r = __builtin_amdgcn_update_dpp(0, __float_as_int(x), 0xB1, 0xF, 0xF, true);
    return __int_as_float(r);
}
__device__ __forceinline__ float dpp_xor2(float x) {
    int r = __builtin_amdgcn_update_dpp(0, __float_as_int(x), 0x4E, 0xF, 0xF, true);
    return __int_as_float(r);
}
__device__ __forceinline__ float sel4(float x0, float x1, float x2, float x3, int m) {
    float lo = (m & 1) ? x1 : x0;
    float hi = (m & 1) ? x3 : x2;
    return (m & 2) ? hi : lo;
}
__device__ __forceinline__ int pack2h(float a, float b) {
    v2h p; p.x = (_Float16)a; p.y = (_Float16)b;
    return __builtin_bit_cast(int, p);
}
#if __has_builtin(__builtin_amdgcn_fdot2)
__device__ __forceinline__ float dot2acc(int wb, int xb, float c) {
    return __builtin_amdgcn_fdot2(__builtin_bit_cast(v2h, wb),
                                  __builtin_bit_cast(v2h, xb), c, false);
}
#else
__device__ __forceinline__ float dot2acc(int wb, int xb, float c) {
    v2h w = __builtin_bit_cast(v2h, wb);
    v2h x = __builtin_bit_cast(v2h, xb);
    c = __builtin_fmaf((float)w.x, (float)x.x, c);
    c = __builtin_fmaf((float)w.y, (float)x.y, c);
    return c;
}
#endif

// ---------------------------------------------------------------------------
// Transpose W [256, K] -> Wt [K, 256] (layer-0 GEMM only)
// ---------------------------------------------------------------------------
__global__ void transpose_w(const float* __restrict__ W, float* __restrict__ Wt, int K) {
    int idx = blockIdx.x * 256 + threadIdx.x;
    if (idx < 256 * K) {
        int n = idx / K, k = idx - n * K;
        Wt[k * 256 + n] = W[idx];
    }
}

// ---------------------------------------------------------------------------
// Input-projection GEMM for layer 0 only (K=128). Proven (round 1).
// ---------------------------------------------------------------------------
template <int K>
__global__ __launch_bounds__(256) void gemm_xp(
    const float* __restrict__ X, const float* __restrict__ Wt,
    const float* __restrict__ b1, const float* __restrict__ b2,
    float* __restrict__ XP)
{
    constexpr int TM = 64;
    constexpr int KC = 16;
    __shared__ __align__(16) float xT[K][TM + 4];
    __shared__ __align__(16) float wc[KC][256];
    const int m0 = blockIdx.x * TM;
    const int t  = threadIdx.x;
    const int cg = (t & 63) * 4;
    const int rg = (t >> 6) * 16;

    for (int idx = t; idx < TM * K; idx += 256) {
        int r = idx / K, k = idx - r * K;
        xT[k][r] = X[(size_t)(m0 + r) * K + k];
    }

    float acc[16][4];
    #pragma unroll
    for (int i = 0; i < 16; ++i)
        #pragma unroll
        for (int j = 0; j < 4; ++j) acc[i][j] = 0.f;

    for (int kc = 0; kc < K; kc += KC) {
        __syncthreads();
        #pragma unroll
        for (int i = 0; i < 4; ++i) {
            int e4 = (t + i * 256) * 4;
            int k = e4 >> 8, n = e4 & 255;
            *(float4*)&wc[k][n] = *(const float4*)&Wt[(size_t)(kc + k) * 256 + n];
        }
        __syncthreads();
        #pragma unroll
        for (int k = 0; k < KC; ++k) {
            float4 w = *(const float4*)&wc[k][cg];
            float xr[16];
            #pragma unroll
            for (int q = 0; q < 4; ++q)
                *(float4*)&xr[q * 4] = *(const float4*)&xT[kc + k][rg + q * 4];
            #pragma unroll
            for (int rr = 0; rr < 16; ++rr) {
                acc[rr][0] += xr[rr] * w.x;
                acc[rr][1] += xr[rr] * w.y;
                acc[rr][2] += xr[rr] * w.z;
                acc[rr][3] += xr[rr] * w.w;
            }
        }
    }

    float bias[4];
    #pragma unroll
    for (int j = 0; j < 4; ++j) bias[j] = b1[cg + j] + b2[cg + j];
    #pragma unroll
    for (int rr = 0; rr < 16; ++rr) {
        float4 o;
        o.x = acc[rr][0] + bias[0];
        o.y = acc[rr][1] + bias[1];
        o.z = acc[rr][2] + bias[2];
        o.w = acc[rr][3] + bias[3];
        *(float4*)&XP[(size_t)(m0 + rg + rr) * 256 + cg] = o;
    }
}

// ---------------------------------------------------------------------------
// Fused 3-layer wavefront-pipelined LSTM scan (round-12 structure).
// KEY FIX vs round 12: the allocator's ~76-84 VGPR ceiling for this kernel is
// immovable (rounds 7/8/9/12 evidence), so the 64-int weight file never fit
// -> per-step reload traffic. Now the Wih file (wib, 32 ints/lane for L1/L2)
// lives in the (otherwise unused) forced-LDS block, in a conflict-free
// [slot][lane] layout (lane-stride 16 B -> linear ds_read_b128). Live set
// drops to ~68 regs -> the recurrent Whh file (wgb) is truly register-
// resident. LDS block stays >80 KiB to keep the 1-block/CU clamp.
// ---------------------------------------------------------------------------
__global__ __attribute__((amdgpu_flat_work_group_size(768, 768)))
__attribute__((amdgpu_waves_per_eu(3, 3)))
void lstm_fused3(
    const float* __restrict__ xp,    // [B*T, 256] layer-0 xp (incl. both biases)
    const float* __restrict__ Whh0,
    const float* __restrict__ Wih1, const float* __restrict__ Whh1,
    const float* __restrict__ bi1, const float* __restrict__ bh1,
    const float* __restrict__ Wih2, const float* __restrict__ Whh2,
    const float* __restrict__ bi2, const float* __restrict__ bh2,
    float* __restrict__ hl)          // [B, 64] layer-2 h at t = NT-1
{
    const int tid = threadIdx.x;
    const int b = blockIdx.x;
    const int L = tid >> 8;            // 0,1,2 (4 waves each)
    const int t256 = tid & 255;
    const int ks = t256 & 3;
    const int u = t256 >> 2;           // 0..63

    // 90112 B LDS: occupancy clamp (1 block/CU). Carve:
    //   [0,768)        hb[3][2][64] f16 h-exchange buffers
    //   [1024,66560)   wib staging: 2 quads x 8 slots x 256 lanes x 16 B
    __shared__ __align__(16) char lds_force[90112];
    _Float16 (*hb)[2][64] = (_Float16 (*)[2][64])lds_force;

    // Recurrent weights (critical path), XOR-permuted, f16x2 in 32 int regs.
    const float* Whh = (L == 0) ? Whh0 : (L == 1) ? Whh1 : Whh2;
    int wgb[4][8];
    #pragma unroll
    for (int j = 0; j < 4; ++j) {
        const float* Wr = Whh + (size_t)(((ks ^ j) * 64) + u) * 64 + ks * 16;
        #pragma unroll
        for (int q = 0; q < 8; ++q) wgb[j][q] = pack2h(Wr[2 * q], Wr[2 * q + 1]);
    }

    if (tid < 192) ((int*)lds_force)[tid] = 0;   // zero hb (768 B)

    // Input-projection weights for layers 1,2: pack and stage into LDS.
    // Layout: base + (L-1)*32768 + slot*4096 + t256*16 ; slot 2j+qb holds
    // q = 4qb..4qb+3 of row-slot j. Lane-linear -> conflict-free b128.
    float bsum = 0.f;
    if (L > 0) {
        const float* Wih = (L == 1) ? Wih1 : Wih2;
        char* wl = lds_force + 1024 + (size_t)(L - 1) * 32768 + t256 * 16;
        #pragma unroll
        for (int j = 0; j < 4; ++j) {
            const float* Wr = Wih + (size_t)(((ks ^ j) * 64) + u) * 64 + ks * 16;
            v4i lo, hi;
            lo.x = pack2h(Wr[0], Wr[1]);   lo.y = pack2h(Wr[2], Wr[3]);
            lo.z = pack2h(Wr[4], Wr[5]);   lo.w = pack2h(Wr[6], Wr[7]);
            hi.x = pack2h(Wr[8], Wr[9]);   hi.y = pack2h(Wr[10], Wr[11]);
            hi.z = pack2h(Wr[12], Wr[13]); hi.w = pack2h(Wr[14], Wr[15]);
            *(v4i*)(wl + (2 * j) * 4096)     = lo;
            *(v4i*)(wl + (2 * j + 1) * 4096) = hi;
        }
        const float* bi = (L == 1) ? bi1 : bi2;
        const float* bh = (L == 1) ? bh1 : bh2;
        bsum = bi[ks * 64 + u] + bh[ks * 64 + u];
    }

    // Per-lane activation constants (gate 2 = tanh)
    const float LOG2E = 1.4426950408889634f;
    const float M = (ks == 2) ? (2.f * LOG2E) : LOG2E;
    const float A = (ks == 2) ? 2.f : 1.f;
    const float Bc = (ks == 2) ? -1.f : 0.f;

    // layer-0 xp prefetch ring (depth 4)
    const float* xpb = xp + (size_t)b * NT * H4 + (ks * 64 + u);
    float xr[4];
    if (L == 0) {
        #pragma unroll
        for (int d = 0; d < 4; ++d) xr[d] = xpb[(size_t)d * H4];
    }

    const char* wrd = lds_force + 1024 + (size_t)(L - 1) * 32768 + t256 * 16;

    asm volatile("s_waitcnt lgkmcnt(0)" ::: "memory");
    __builtin_amdgcn_s_barrier();
    __builtin_amdgcn_sched_barrier(0);

    float c = 0.f, h = 0.f;
    const bool writer = (ks == 0);

    for (int s = 0; s < NT + 2; ++s) {
        const int t = s - L;
        const bool active = (t >= 0) && (t < NT);
        if (active) {
            // ---- own-h matvec over k-slice ks (wgb register-resident) ----
            const int* hv = (const int*)&hb[L][t & 1][ks * 16];
            int hh[8];
            #pragma unroll
            for (int q = 0; q < 8; ++q) hh[q] = hv[q];
            float p[4];
            #pragma unroll
            for (int j = 0; j < 4; ++j) {
                float a0 = 0.f, a1 = 0.f;
                #pragma unroll
                for (int q = 0; q < 8; q += 2) {
                    a0 = dot2acc(wgb[j][q], hh[q], a0);
                    a1 = dot2acc(wgb[j][q + 1], hh[q + 1], a1);
                }
                p[j] = a0 + a1;
            }

            float xc;
            if (L == 0) {
                xc = xr[t & 3];
                int tn = t + 4; if (tn > NT - 1) tn = NT - 1;
                xr[t & 3] = xpb[(size_t)tn * H4];     // fire-and-forget refill
            } else {
                // ---- fused input projection: wib streamed from LDS ----
                const int* gv = (const int*)&hb[L - 1][(t + 1) & 1][ks * 16];
                int gg[8];
                #pragma unroll
                for (int q = 0; q < 8; ++q) gg[q] = gv[q];
                #pragma unroll
                for (int j = 0; j < 4; ++j) {
                    v4i wa = *(const v4i*)(wrd + (2 * j) * 4096);
                    v4i wb = *(const v4i*)(wrd + (2 * j + 1) * 4096);
                    float a0 = dot2acc(wa.x, gg[0], 0.f);
                    float a1 = dot2acc(wa.y, gg[1], 0.f);
                    a0 = dot2acc(wa.z, gg[2], a0);
                    a1 = dot2acc(wa.w, gg[3], a1);
                    a0 = dot2acc(wb.x, gg[4], a0);
                    a1 = dot2acc(wb.y, gg[5], a1);
                    a0 = dot2acc(wb.z, gg[6], a0);
                    a1 = dot2acc(wb.w, gg[7], a1);
                    p[j] += a0 + a1;
                }
                xc = bsum;
            }

            // ---- reduce-scatter: full pre-activation of OWN gate ks ----
            float S = p[0] + dpp_xor1(p[1]);
            float t3 = dpp_xor2(dpp_xor1(p[3]));
            S += dpp_xor2(p[2]) + t3;
            float pre = S + xc;

            // ---- single branchless activation chain ----
            float e = __builtin_amdgcn_exp2f(-(pre * M));
            float y = __builtin_amdgcn_rcpf(1.f + e);
            float act = __builtin_fmaf(A, y, Bc);

            // ---- allgather + gate extraction ----
            float a1g = dpp_xor1(act);
            float a2g = dpp_xor2(act);
            float a3g = dpp_xor2(a1g);
            float ig = (ks & 1) ? (a1g * a3g) : (act * a2g);   // i*g
            float fv = sel4(a1g, act, a3g, a2g, ks);           // f
            float ov = sel4(a3g, a2g, a1g, act, ks);           // o

            // ---- cell update (redundant x4, identical bits) ----
            c = __builtin_fmaf(fv, c, ig);
            float e2 = __builtin_amdgcn_exp2f(-(c * (2.f * LOG2E)));
            float y2 = __builtin_amdgcn_rcpf(1.f + e2);
            float th = __builtin_fmaf(2.f, y2, -1.f);
            h = ov * th;

            if (writer) {
                hb[L][(t + 1) & 1][u] = (_Float16)h;   // parity no reader touches
                if (L == 2 && t == NT - 1) hl[(size_t)b * 64 + u] = h;
            }
        }
        asm volatile("s_waitcnt lgkmcnt(0)" ::: "memory");
        __builtin_amdgcn_s_barrier();
        __builtin_amdgcn_sched_barrier(0);
    }
}

// ---------------------------------------------------------------------------
// Final linear: out[b][o] = b_out[o] + sum_j h_last[b][j] * W_out[o][j]
// ---------------------------------------------------------------------------
__global__ __launch_bounds__(256) void final_linear(
    const float* __restrict__ hlv, const float* __restrict__ Wout,
    const float* __restrict__ bout, float* __restrict__ out)
{
    __shared__ float w[128];
    int t = threadIdx.x;
    if (t < 128) w[t] = Wout[t];
    __syncthreads();
    const float* h = hlv + (size_t)t * 64;
    float a0 = bout[0], a1 = bout[1];
    #pragma unroll 8
    for (int j = 0; j < 64; ++j) {
        float hv = h[j];
        a0 += hv * w[j];
        a1 += hv * w[64 + j];
    }
    out[t * 2 + 0] = a0;
    out[t * 2 + 1] = a1;
}

// ---------------------------------------------------------------------------
extern "C" void kernel_launch(void* const* d_in, const int* in_sizes, int n_in,
                              void* d_out, int out_size, void* d_ws, size_t ws_size,
                              hipStream_t stream)
{
    const float* x     = (const float*)d_in[0];
    const float* W_ih0 = (const float*)d_in[1];
    const float* W_hh0 = (const float*)d_in[2];
    const float* b_ih0 = (const float*)d_in[3];
    const float* b_hh0 = (const float*)d_in[4];
    const float* W_ih1 = (const float*)d_in[5];
    const float* W_hh1 = (const float*)d_in[6];
    const float* b_ih1 = (const float*)d_in[7];
    const float* b_hh1 = (const float*)d_in[8];
    const float* W_ih2 = (const float*)d_in[9];
    const float* W_hh2 = (const float*)d_in[10];
    const float* b_ih2 = (const float*)d_in[11];
    const float* b_hh2 = (const float*)d_in[12];
    const float* W_out = (const float*)d_in[13];
    const float* b_out = (const float*)d_in[14];
    float* out = (float*)d_out;

    const size_t M = (size_t)NB * NT;                  // 131072
    const size_t XP_BYTES  = M * H4 * sizeof(float);   // 128 MiB
    const size_t WT0_BYTES = 128 * 256 * sizeof(float);
    const size_t HL_BYTES  = NB * 64 * sizeof(float);
    if (ws_size < XP_BYTES + WT0_BYTES + HL_BYTES)
        return;

    char* ws = (char*)d_ws;
    float* XP  = (float*)ws;
    float* WT0 = (float*)(ws + XP_BYTES);
    float* HL  = WT0 + 128 * 256;

    // Layer-0 input projection (parallel GEMM) — layers 1,2 are fused.
    transpose_w<<<128, 256, 0, stream>>>(W_ih0, WT0, 128);
    gemm_xp<128><<<(int)(M / 64), 256, 0, stream>>>(x, WT0, b_ih0, b_hh0, XP);

    // Fused 3-layer pipelined scan (1 block/CU enforced via LDS).
    lstm_fused3<<<NB, 768, 0, stream>>>(XP, W_hh0,
                                        W_ih1, W_hh1, b_ih1, b_hh1,
                                        W_ih2, W_hh2, b_ih2, b_hh2, HL);

    // Final projection.
    final_linear<<<1, 256, 0, stream>>>(HL, W_out, b_out, out);
}

// Round 14
// 465.298 us; speedup vs baseline: 1.1378x; 1.1378x over previous
//
#include <hip/hip_runtime.h>
#include <cstddef>
#include <cstdint>

// Problem constants (from reference): B=256, T=512, I=128, H=64, 4H=256.
#define NB 256
#define NT 512
#define H4 256

typedef _Float16 v2h __attribute__((ext_vector_type(2)));
typedef int v4i __attribute__((ext_vector_type(4)));

// Quad-lane exchange via DPP quad_perm (pure VALU):
// xor1: perm(1,0,3,2)=0xB1 ; xor2: perm(2,3,0,1)=0x4E
__device__ __forceinline__ float dpp_xor1(float x) {
    int r = __builtin_amdgcn_update_dpp(0, __float_as_int(x), 0xB1, 0xF, 0xF, true);
    return __int_as_float(r);
}
__device__ __forceinline__ float dpp_xor2(float x) {
    int r = __builtin_amdgcn_update_dpp(0, __float_as_int(x), 0x4E, 0xF, 0xF, true);
    return __int_as_float(r);
}
__device__ __forceinline__ float sel4(float x0, float x1, float x2, float x3, int m) {
    float lo = (m & 1) ? x1 : x0;
    float hi = (m & 1) ? x3 : x2;
    return (m & 2) ? hi : lo;
}
__device__ __forceinline__ int pack2h(float a, float b) {
    v2h p; p.x = (_Float16)a; p.y = (_Float16)b;
    return __builtin_bit_cast(int, p);
}
#if __has_builtin(__builtin_amdgcn_fdot2)
__device__ __forceinline__ float dot2acc(int wb, int xb, float c) {
    return __builtin_amdgcn_fdot2(__builtin_bit_cast(v2h, wb),
                                  __builtin_bit_cast(v2h, xb), c, false);
}
#else
__device__ __forceinline__ float dot2acc(int wb, int xb, float c) {
    v2h w = __builtin_bit_cast(v2h, wb);
    v2h x = __builtin_bit_cast(v2h, xb);
    c = __builtin_fmaf((float)w.x, (float)x.x, c);
    c = __builtin_fmaf((float)w.y, (float)x.y, c);
    return c;
}
#endif

__device__ __forceinline__ void mv4(const int wq[4][8], const int hh[8], float p[4]) {
    #pragma unroll
    for (int j = 0; j < 4; ++j) {
        float a0 = 0.f, a1 = 0.f;
        #pragma unroll
        for (int q = 0; q < 8; q += 2) {
            a0 = dot2acc(wq[j][q], hh[q], a0);
            a1 = dot2acc(wq[j][q + 1], hh[q + 1], a1);
        }
        p[j] = a0 + a1;
    }
}
__device__ __forceinline__ void mv4acc(const int wq[4][8], const int hh[8], float p[4]) {
    #pragma unroll
    for (int j = 0; j < 4; ++j) {
        float a0 = 0.f, a1 = 0.f;
        #pragma unroll
        for (int q = 0; q < 8; q += 2) {
            a0 = dot2acc(wq[j][q], hh[q], a0);
            a1 = dot2acc(wq[j][q + 1], hh[q + 1], a1);
        }
        p[j] += a0 + a1;
    }
}

// ---------------------------------------------------------------------------
// Transpose W [256, K] -> Wt [K, 256] (layer-0 GEMM only)
// ---------------------------------------------------------------------------
__global__ void transpose_w(const float* __restrict__ W, float* __restrict__ Wt, int K) {
    int idx = blockIdx.x * 256 + threadIdx.x;
    if (idx < 256 * K) {
        int n = idx / K, k = idx - n * K;
        Wt[k * 256 + n] = W[idx];
    }
}

// ---------------------------------------------------------------------------
// Input-projection GEMM for layer 0 only (K=128). Proven (round 1).
// ---------------------------------------------------------------------------
template <int K>
__global__ __launch_bounds__(256) void gemm_xp(
    const float* __restrict__ X, const float* __restrict__ Wt,
    const float* __restrict__ b1, const float* __restrict__ b2,
    float* __restrict__ XP)
{
    constexpr int TM = 64;
    constexpr int KC = 16;
    __shared__ __align__(16) float xT[K][TM + 4];
    __shared__ __align__(16) float wc[KC][256];
    const int m0 = blockIdx.x * TM;
    const int t  = threadIdx.x;
    const int cg = (t & 63) * 4;
    const int rg = (t >> 6) * 16;

    for (int idx = t; idx < TM * K; idx += 256) {
        int r = idx / K, k = idx - r * K;
        xT[k][r] = X[(size_t)(m0 + r) * K + k];
    }

    float acc[16][4];
    #pragma unroll
    for (int i = 0; i < 16; ++i)
        #pragma unroll
        for (int j = 0; j < 4; ++j) acc[i][j] = 0.f;

    for (int kc = 0; kc < K; kc += KC) {
        __syncthreads();
        #pragma unroll
        for (int i = 0; i < 4; ++i) {
            int e4 = (t + i * 256) * 4;
            int k = e4 >> 8, n = e4 & 255;
            *(float4*)&wc[k][n] = *(const float4*)&Wt[(size_t)(kc + k) * 256 + n];
        }
        __syncthreads();
        #pragma unroll
        for (int k = 0; k < KC; ++k) {
            float4 w = *(const float4*)&wc[k][cg];
            float xr[16];
            #pragma unroll
            for (int q = 0; q < 4; ++q)
                *(float4*)&xr[q * 4] = *(const float4*)&xT[kc + k][rg + q * 4];
            #pragma unroll
            for (int rr = 0; rr < 16; ++rr) {
                acc[rr][0] += xr[rr] * w.x;
                acc[rr][1] += xr[rr] * w.y;
                acc[rr][2] += xr[rr] * w.z;
                acc[rr][3] += xr[rr] * w.w;
            }
        }
    }

    float bias[4];
    #pragma unroll
    for (int j = 0; j < 4; ++j) bias[j] = b1[cg + j] + b2[cg + j];
    #pragma unroll
    for (int rr = 0; rr < 16; ++rr) {
        float4 o;
        o.x = acc[rr][0] + bias[0];
        o.y = acc[rr][1] + bias[1];
        o.z = acc[rr][2] + bias[2];
        o.w = acc[rr][3] + bias[3];
        *(float4*)&XP[(size_t)(m0 + rg + rr) * 256 + cg] = o;
    }
}

// ---------------------------------------------------------------------------
// Fused 3-layer wavefront-pipelined LSTM scan.
// vs round 12 (best, 427 us): same data layout (wib back in registers), but
// the step loop is restructured to cut VALU issue:
//  - readfirstlane(L): role branches provably wave-uniform -> s_cbranch, each
//    wave only fetches its own role's code (no exec-masked waste)
//  - 4x unrolled step loop: all hb parities and xr ring slots are literals;
//    LDS addresses are 4 precomputed per-lane pointers -> zero per-step
//    address arithmetic
//  - pre-negated activation constants
// LDS 90112 B clamp (1 block/CU, 12 waves) retained — round 12's real win.
// ---------------------------------------------------------------------------
__global__ __attribute__((amdgpu_flat_work_group_size(768, 768)))
__attribute__((amdgpu_waves_per_eu(3, 3)))
void lstm_fused3(
    const float* __restrict__ xp,    // [B*T, 256] layer-0 xp (incl. both biases)
    const float* __restrict__ Whh0,
    const float* __restrict__ Wih1, const float* __restrict__ Whh1,
    const float* __restrict__ bi1, const float* __restrict__ bh1,
    const float* __restrict__ Wih2, const float* __restrict__ Whh2,
    const float* __restrict__ bi2, const float* __restrict__ bh2,
    float* __restrict__ hl)          // [B, 64] layer-2 h at t = NT-1
{
    const int tid = threadIdx.x;
    const int b = blockIdx.x;
    const int L = tid >> 8;            // 0,1,2 (4 waves each)
    const int t256 = tid & 255;
    const int ks = t256 & 3;
    const int u = t256 >> 2;           // 0..63

    __shared__ __align__(16) char lds_force[90112];   // 1 block/CU clamp
    _Float16 (*hb)[2][64] = (_Float16 (*)[2][64])lds_force;

    const int Lu = __builtin_amdgcn_readfirstlane(L);   // wave-uniform role

    // Recurrent weights, XOR-permuted: slot j = gate (ks^j), k-slice ks.
    const float* Whh = (Lu == 0) ? Whh0 : (Lu == 1) ? Whh1 : Whh2;
    int wgb[4][8];
    #pragma unroll
    for (int j = 0; j < 4; ++j) {
        const float* Wr = Whh + (size_t)(((ks ^ j) * 64) + u) * 64 + ks * 16;
        #pragma unroll
        for (int q = 0; q < 8; ++q) wgb[j][q] = pack2h(Wr[2 * q], Wr[2 * q + 1]);
    }
    int wib[4][8];
    float bsum = 0.f;
    if (Lu > 0) {
        const float* Wih = (Lu == 1) ? Wih1 : Wih2;
        #pragma unroll
        for (int j = 0; j < 4; ++j) {
            const float* Wr = Wih + (size_t)(((ks ^ j) * 64) + u) * 64 + ks * 16;
            #pragma unroll
            for (int q = 0; q < 8; ++q) wib[j][q] = pack2h(Wr[2 * q], Wr[2 * q + 1]);
        }
        const float* bi = (Lu == 1) ? bi1 : bi2;
        const float* bh = (Lu == 1) ? bh1 : bh2;
        bsum = bi[ks * 64 + u] + bh[ks * 64 + u];
    }

    // Pre-negated activation constants (gate 2 = tanh)
    const float LOG2E = 1.4426950408889634f;
    const float nM  = (ks == 2) ? (-2.f * LOG2E) : -LOG2E;
    const float A   = (ks == 2) ? 2.f : 1.f;
    const float Bc  = (ks == 2) ? -1.f : 0.f;
    const float nMt = -2.f * LOG2E;

    if (tid < 192) ((int*)lds_force)[tid] = 0;   // zero hb (768 B)

    // Precomputed per-lane LDS pointers (both parities; no per-step addr math)
    const v4i* pOwn0 = (const v4i*)&hb[Lu][0][ks * 16];
    const v4i* pOwn1 = (const v4i*)&hb[Lu][1][ks * 16];
    const int Lin = (Lu > 0) ? (Lu - 1) : 0;
    const v4i* pIn0 = (const v4i*)&hb[Lin][0][ks * 16];
    const v4i* pIn1 = (const v4i*)&hb[Lin][1][ks * 16];
    _Float16* pW0 = &hb[Lu][0][u];
    _Float16* pW1 = &hb[Lu][1][u];

    // layer-0 xp prefetch ring (depth 4)
    const float* xpb = xp + (size_t)b * NT * H4 + (ks * 64 + u);
    float xr[4];
    if (Lu == 0) {
        #pragma unroll
        for (int d = 0; d < 4; ++d) xr[d] = xpb[(size_t)d * H4];
    }

    asm volatile("s_waitcnt lgkmcnt(0)" ::: "memory");
    __builtin_amdgcn_s_barrier();
    __builtin_amdgcn_sched_barrier(0);

    float c = 0.f, h = 0.f;
    const bool writer = (ks == 0);

#define BAR() do { asm volatile("s_waitcnt lgkmcnt(0)" ::: "memory"); \
                   __builtin_amdgcn_s_barrier(); \
                   __builtin_amdgcn_sched_barrier(0); } while (0)

#define LD8(dst, ptr) do { v4i t0_ = (ptr)[0]; v4i t1_ = (ptr)[1]; \
    dst[0] = t0_.x; dst[1] = t0_.y; dst[2] = t0_.z; dst[3] = t0_.w; \
    dst[4] = t1_.x; dst[5] = t1_.y; dst[6] = t1_.z; dst[7] = t1_.w; } while (0)

#define RED(S, p) float S = p[0] + dpp_xor1(p[1]); \
    S += dpp_xor2(p[2]) + dpp_xor2(dpp_xor1(p[3]))

#define ACT_CELL(pre) do { \
    float e_ = __builtin_amdgcn_exp2f((pre) * nM); \
    float y_ = __builtin_amdgcn_rcpf(1.f + e_); \
    float act_ = __builtin_fmaf(A, y_, Bc); \
    float a1_ = dpp_xor1(act_), a2_ = dpp_xor2(act_), a3_ = dpp_xor2(a1_); \
    float ig_ = (ks & 1) ? (a1_ * a3_) : (act_ * a2_); \
    float fv_ = sel4(a1_, act_, a3_, a2_, ks); \
    float ov_ = sel4(a3_, a2_, a1_, act_, ks); \
    c = __builtin_fmaf(fv_, c, ig_); \
    float e2_ = __builtin_amdgcn_exp2f(c * nMt); \
    float y2_ = __builtin_amdgcn_rcpf(1.f + e2_); \
    h = ov_ * __builtin_fmaf(2.f, y2_, -1.f); \
} while (0)

// L0: t = s. read hb[0][D&1], write hb[0][(D+1)&1], xr slot D.
#define STEP0(D) do { int s_ = s4 + (D); if (s_ < NT) { \
    int hh[8]; LD8(hh, (((D) & 1) ? pOwn1 : pOwn0)); \
    float p[4]; mv4(wgb, hh, p); \
    float xc = xr[(D)]; \
    int tn_ = s_ + 4; if (tn_ > NT - 1) tn_ = NT - 1; \
    xr[(D)] = xpb[(size_t)tn_ * H4]; \
    RED(S_, p); float pre_ = S_ + xc; \
    ACT_CELL(pre_); \
    if (writer) *((((D) + 1) & 1) ? pW1 : pW0) = (_Float16)h; \
} } while (0)

// L1: t = s-1. own hb[1][(D+1)&1], gg hb[0][D&1], write hb[1][D&1].
#define STEP1(D) do { int t_ = s4 + (D) - 1; if ((unsigned)t_ < NT) { \
    int hh[8]; LD8(hh, ((((D) + 1) & 1) ? pOwn1 : pOwn0)); \
    float p[4]; mv4(wgb, hh, p); \
    int gg[8]; LD8(gg, (((D) & 1) ? pIn1 : pIn0)); \
    mv4acc(wib, gg, p); \
    RED(S_, p); float pre_ = S_ + bsum; \
    ACT_CELL(pre_); \
    if (writer) *(((D) & 1) ? pW1 : pW0) = (_Float16)h; \
} } while (0)

// L2: t = s-2. own hb[2][D&1], gg hb[1][(D+1)&1], write hb[2][(D+1)&1].
#define STEP2(D) do { int t_ = s4 + (D) - 2; if ((unsigned)t_ < NT) { \
    int hh[8]; LD8(hh, (((D) & 1) ? pOwn1 : pOwn0)); \
    float p[4]; mv4(wgb, hh, p); \
    int gg[8]; LD8(gg, ((((D) + 1) & 1) ? pIn1 : pIn0)); \
    mv4acc(wib, gg, p); \
    RED(S_, p); float pre_ = S_ + bsum; \
    ACT_CELL(pre_); \
    if (writer) { \
        *((((D) + 1) & 1) ? pW1 : pW0) = (_Float16)h; \
        if (t_ == NT - 1) hl[(size_t)b * 64 + u] = h; \
    } \
} } while (0)

    for (int s4 = 0; s4 < NT + 4; s4 += 4) {
        if (Lu == 0) {
            STEP0(0); BAR(); STEP0(1); BAR(); STEP0(2); BAR(); STEP0(3); BAR();
        } else if (Lu == 1) {
            STEP1(0); BAR(); STEP1(1); BAR(); STEP1(2); BAR(); STEP1(3); BAR();
        } else {
            STEP2(0); BAR(); STEP2(1); BAR(); STEP2(2); BAR(); STEP2(3); BAR();
        }
    }
#undef STEP0
#undef STEP1
#undef STEP2
#undef ACT_CELL
#undef RED
#undef LD8
#undef BAR
}

// ---------------------------------------------------------------------------
// Final linear: out[b][o] = b_out[o] + sum_j h_last[b][j] * W_out[o][j]
// ---------------------------------------------------------------------------
__global__ __launch_bounds__(256) void final_linear(
    const float* __restrict__ hlv, const float* __restrict__ Wout,
    const float* __restrict__ bout, float* __restrict__ out)
{
    __shared__ float w[128];
    int t = threadIdx.x;
    if (t < 128) w[t] = Wout[t];
    __syncthreads();
    const float* h = hlv + (size_t)t * 64;
    float a0 = bout[0], a1 = bout[1];
    #pragma unroll 8
    for (int j = 0; j < 64; ++j) {
        float hv = h[j];
        a0 += hv * w[j];
        a1 += hv * w[64 + j];
    }
    out[t * 2 + 0] = a0;
    out[t * 2 + 1] = a1;
}

// ---------------------------------------------------------------------------
extern "C" void kernel_launch(void* const* d_in, const int* in_sizes, int n_in,
                              void* d_out, int out_size, void* d_ws, size_t ws_size,
                              hipStream_t stream)
{
    const float* x     = (const float*)d_in[0];
    const float* W_ih0 = (const float*)d_in[1];
    const float* W_hh0 = (const float*)d_in[2];
    const float* b_ih0 = (const float*)d_in[3];
    const float* b_hh0 = (const float*)d_in[4];
    const float* W_ih1 = (const float*)d_in[5];
    const float* W_hh1 = (const float*)d_in[6];
    const float* b_ih1 = (const float*)d_in[7];
    const float* b_hh1 = (const float*)d_in[8];
    const float* W_ih2 = (const float*)d_in[9];
    const float* W_hh2 = (const float*)d_in[10];
    const float* b_ih2 = (const float*)d_in[11];
    const float* b_hh2 = (const float*)d_in[12];
    const float* W_out = (const float*)d_in[13];
    const float* b_out = (const float*)d_in[14];
    float* out = (float*)d_out;

    const size_t M = (size_t)NB * NT;                  // 131072
    const size_t XP_BYTES  = M * H4 * sizeof(float);   // 128 MiB
    const size_t WT0_BYTES = 128 * 256 * sizeof(float);
    const size_t HL_BYTES  = NB * 64 * sizeof(float);
    if (ws_size < XP_BYTES + WT0_BYTES + HL_BYTES)
        return;

    char* ws = (char*)d_ws;
    float* XP  = (float*)ws;
    float* WT0 = (float*)(ws + XP_BYTES);
    float* HL  = WT0 + 128 * 256;

    // Layer-0 input projection (parallel GEMM) — layers 1,2 are fused.
    transpose_w<<<128, 256, 0, stream>>>(W_ih0, WT0, 128);
    gemm_xp<128><<<(int)(M / 64), 256, 0, stream>>>(x, WT0, b_ih0, b_hh0, XP);

    // Fused 3-layer pipelined scan (1 block/CU enforced via LDS).
    lstm_fused3<<<NB, 768, 0, stream>>>(XP, W_hh0,
                                        W_ih1, W_hh1, b_ih1, b_hh1,
                                        W_ih2, W_hh2, b_ih2, b_hh2, HL);

    // Final projection.
    final_linear<<<1, 256, 0, stream>>>(HL, W_out, b_out, out);
}